// Round 8
// baseline (3906.607 us; speedup 1.0000x reference)
//
#include <hip/hip_runtime.h>

typedef unsigned short u16;
typedef unsigned int u32;
typedef unsigned long long u64;
typedef __attribute__((ext_vector_type(8))) short bf16x8;   // 8 bf16 (4 VGPRs)
typedef __attribute__((ext_vector_type(4))) float f32x4;

#define T_STEPS 1024
#define E_SZ 128
#define U_SZ 256

#define NG 16    // batch groups (16 batches each)
#define MB 16    // batch rows per group
#define NSL 8    // slices per layer (8 L0-wgs + 8 L1-wgs per group)
#define RD 8     // h0 ring depth
#define HS 264   // padded LDS row stride, K=256
#define EPAD 136 // padded LDS row stride, K=128
#define BSTRIDE 192  // u64 per slice-block: 16 batches x 12 tagged u64

#define POLL_BAIL 60000   // latched fast-fail: broken protocol -> quick wrong answer

// ---- LDS layout (role-dependent), bytes ----
#define L0_W0T 0
#define L0_R0T 34816
#define L0_X   102400
#define L0_STG 106752
#define L0_B   114944
#define L1_W1T 0
#define L1_R1T 67584
#define L1_SG0 135168
#define L1_SG1 143360
#define L1_B   151552
#define L1_EPIF 152064
#define SMEM_TOTAL 154624

// ---- exchange state: self-verifying tagged u64 = {3x bf16 | tag16} ----
// Wire format UNCHANGED since R2 (proven). Weight columns inside each wg are
// permuted unit-major (n = u*4 + gate) so each wave owns all 4 gates of its
// 8 units -> cell update is in-wave (shfl butterfly), no ldsG, no extra
// barrier, earlier post on the pacing path.
__device__ u64 g_exH0[RD * NG * NSL * BSTRIDE];  // 1.5 MiB h0 ring
__device__ u64 g_exH1[2 * NG * NSL * BSTRIDE];   // h1 parity ring
__device__ int g_pr[NG * NSL * 16];              // L1 consume progress (ring guard)
__device__ u32 g_run;                            // run/generation counter
__device__ int g_isF32;

__device__ __forceinline__ float bf2f(u16 u) {
  union { u32 i; float f; } v; v.i = ((u32)u) << 16; return v.f;
}
__device__ __forceinline__ u16 f2bf(float f) {
  union { u32 i; float f; } v; v.f = f;
  u32 r = v.i + 0x7fffu + ((v.i >> 16) & 1u);
  return (u16)(r >> 16);
}
__device__ __forceinline__ float sig_(float x) { return 1.f / (1.f + __expf(-x)); }
__device__ __forceinline__ float tnh_(float x) { return 2.f / (1.f + __expf(-2.f * x)) - 1.f; }

// ---- dtype probe: bumps run counter, zeroes ring guard ----
extern "C" __global__ void dtype_probe(const void* W0v) {
  __shared__ int cntBig;
  if (threadIdx.x == 0) cntBig = 0;
  __syncthreads();
  const u16* u = (const u16*)W0v;
  int big = 0;
  for (int i = threadIdx.x; i < 4096; i += 256)
    if ((u[i] & 0x7F80u) >= 0x4100u) big++;
  atomicAdd(&cntBig, big);
  __syncthreads();
  for (int i = threadIdx.x; i < NG * NSL * 16; i += 256) g_pr[i] = 0;
  if (threadIdx.x == 0) {
    g_isF32 = (cntBig > 100) ? 1 : 0;
    g_run = g_run + 1;               // fresh tag generation each launch
  }
}

__device__ __forceinline__ u64 ldAtom(const u64* p) {
  return __hip_atomic_load(p, __ATOMIC_RELAXED, __HIP_MEMORY_SCOPE_AGENT);
}

// ---- ring-guard poll returning min observed progress (amortizes re-polls) ----
__device__ __forceinline__ int wavePollMin(const int* fA, int tgt, int lane,
                                           int& dead) {
  if (dead) return tgt;
  const int* p = (lane < 8) ? fA + lane * 16 : nullptr;
  int ok = (p == nullptr);
  int v = 0x7fffffff;
  int it = 0;
  while (!__all(ok)) {
    if (!ok) {
      v = __hip_atomic_load(p, __ATOMIC_RELAXED, __HIP_MEMORY_SCOPE_AGENT);
      ok = v >= tgt;
    }
    if (++it > POLL_BAIL) { dead = 1; break; }
    if (it > 48) __builtin_amdgcn_s_sleep(1);
  }
  __atomic_signal_fence(__ATOMIC_ACQUIRE);
  int m = (lane < 8) ? v : 0x7fffffff;
#pragma unroll
  for (int off = 4; off; off >>= 1) {
    int o = __shfl_down(m, off);
    m = m < o ? m : o;
  }
  return __shfl(m, 0);
}

// ---- unpack 3 tagged u64 -> 16B fragment, write to LDS staging ----
__device__ __forceinline__ void unpackToLds(const u64 q0, const u64 q1, const u64 q2,
                                            u16* __restrict__ stg, int slice,
                                            int ml, int quad) {
  u32 a0 = (u32)q0, a1 = (u32)(q0 >> 32);
  u32 b0 = (u32)q1, b1 = (u32)(q1 >> 32);
  u32 c0 = (u32)q2;
  uint4 F;
  F.x = a0;
  F.y = (a1 & 0xFFFFu) | (b0 << 16);
  F.z = (b0 >> 16) | (b1 << 16);
  F.w = c0;
  *(uint4*)(stg + (((slice << 4) + ml) * 4 + quad) * 8) = F;
}

// ---- wave-split staged gather, ONE ring: wave wv polls+stages slices
// {2wv, 2wv+1}; lane (ml,quad) owns 3 u64 per slice. ----
__device__ __forceinline__ void stageOne(const u64* __restrict__ base, u32 etag,
                                         u16* __restrict__ stg,
                                         int wv, int ml, int quad, int& dead) {
  const int j0 = wv << 1;
  const u64* p0 = base + (u64)j0 * BSTRIDE + ml * 12 + quad * 3;
  const u64* p1 = p0 + BSTRIDE;
  u64 qa0 = ldAtom(p0), qa1 = ldAtom(p0 + 1), qa2 = ldAtom(p0 + 2);
  u64 qb0 = ldAtom(p1), qb1 = ldAtom(p1 + 1), qb2 = ldAtom(p1 + 2);
  int it = 0;
  while (true) {
    u32 badA = (((u32)(qa0 >> 48)) ^ etag) | (((u32)(qa1 >> 48)) ^ etag) |
               (((u32)(qa2 >> 48)) ^ etag);
    u32 badB = (((u32)(qb0 >> 48)) ^ etag) | (((u32)(qb1 >> 48)) ^ etag) |
               (((u32)(qb2 >> 48)) ^ etag);
    if (!__any((badA | badB) != 0)) break;
    if (dead) break;
    if (++it > POLL_BAIL) { dead = 1; break; }
    if (badA) { qa0 = ldAtom(p0); qa1 = ldAtom(p0 + 1); qa2 = ldAtom(p0 + 2); }
    if (badB) { qb0 = ldAtom(p1); qb1 = ldAtom(p1 + 1); qb2 = ldAtom(p1 + 2); }
    if (it > 8) __builtin_amdgcn_s_sleep(1);
  }
  __atomic_signal_fence(__ATOMIC_ACQUIRE);
  unpackToLds(qa0, qa1, qa2, stg, j0, ml, quad);
  unpackToLds(qb0, qb1, qb2, stg, j0 + 1, ml, quad);
}

// ---- wave-split staged gather, BOTH rings fused (L1) ----
__device__ __forceinline__ void stageDual(const u64* __restrict__ b0, u32 e0,
                                          u16* __restrict__ s0,
                                          const u64* __restrict__ b1, u32 e1,
                                          u16* __restrict__ s1, int doH1,
                                          int wv, int ml, int quad, int& dead) {
  const int j0 = wv << 1;
  const int off = ml * 12 + quad * 3;
  const u64* p0a = b0 + (u64)j0 * BSTRIDE + off;
  const u64* p0b = p0a + BSTRIDE;
  const u64* p1a = b1 + (u64)j0 * BSTRIDE + off;
  const u64* p1b = p1a + BSTRIDE;
  u64 xa0 = ldAtom(p0a), xa1 = ldAtom(p0a + 1), xa2 = ldAtom(p0a + 2);
  u64 xb0 = ldAtom(p0b), xb1 = ldAtom(p0b + 1), xb2 = ldAtom(p0b + 2);
  u64 ya0 = 0, ya1 = 0, ya2 = 0, yb0 = 0, yb1 = 0, yb2 = 0;
  if (doH1) {
    ya0 = ldAtom(p1a); ya1 = ldAtom(p1a + 1); ya2 = ldAtom(p1a + 2);
    yb0 = ldAtom(p1b); yb1 = ldAtom(p1b + 1); yb2 = ldAtom(p1b + 2);
  }
  int it = 0;
  while (true) {
    u32 badA = (((u32)(xa0 >> 48)) ^ e0) | (((u32)(xa1 >> 48)) ^ e0) |
               (((u32)(xa2 >> 48)) ^ e0);
    u32 badB = (((u32)(xb0 >> 48)) ^ e0) | (((u32)(xb1 >> 48)) ^ e0) |
               (((u32)(xb2 >> 48)) ^ e0);
    u32 badC = 0, badD = 0;
    if (doH1) {
      badC = (((u32)(ya0 >> 48)) ^ e1) | (((u32)(ya1 >> 48)) ^ e1) |
             (((u32)(ya2 >> 48)) ^ e1);
      badD = (((u32)(yb0 >> 48)) ^ e1) | (((u32)(yb1 >> 48)) ^ e1) |
             (((u32)(yb2 >> 48)) ^ e1);
    }
    if (!__any((badA | badB | badC | badD) != 0)) break;
    if (dead) break;
    if (++it > POLL_BAIL) { dead = 1; break; }
    if (badA) { xa0 = ldAtom(p0a); xa1 = ldAtom(p0a + 1); xa2 = ldAtom(p0a + 2); }
    if (badB) { xb0 = ldAtom(p0b); xb1 = ldAtom(p0b + 1); xb2 = ldAtom(p0b + 2); }
    if (badC) { ya0 = ldAtom(p1a); ya1 = ldAtom(p1a + 1); ya2 = ldAtom(p1a + 2); }
    if (badD) { yb0 = ldAtom(p1b); yb1 = ldAtom(p1b + 1); yb2 = ldAtom(p1b + 2); }
    if (it > 8) __builtin_amdgcn_s_sleep(1);
  }
  __atomic_signal_fence(__ATOMIC_ACQUIRE);
  unpackToLds(xa0, xa1, xa2, s0, j0, ml, quad);
  unpackToLds(xb0, xb1, xb2, s0, j0 + 1, ml, quad);
  if (doH1) {
    unpackToLds(ya0, ya1, ya2, s1, j0, ml, quad);
    unpackToLds(yb0, yb1, yb2, s1, j0 + 1, ml, quad);
  }
}

// ---- in-wave gate nonlin + butterfly cell update + bpermute post.
// Column layout is unit-major (n = u*4 + gate): lane (ml,quad) holds gate
// (ml&3) of units {8wv+(ml>>2), 8wv+4+(ml>>2)} for batches 4quad+r.
// 4-lane butterfly distributes i,f,g,o; c-state in regs (4x redundant,
// bit-identical). h routed to 48 posting lanes via 3 ds_bpermute. ----
__device__ __forceinline__ void gateCellPost(f32x4 acA, f32x4 acB,
                                             float* cstA, float* cstB,
                                             int lane, int wv, u32 etag,
                                             u64* __restrict__ exch, u64 blk) {
  const int ml = lane & 15;
  const int gg = ml & 3;
  const int isT = (gg == 2);
  u32 hpack = 0;
#pragma unroll
  for (int r = 0; r < 4; r++) {
    float vA = isT ? tnh_(acA[r]) : sig_(acA[r]);
    float vB = isT ? tnh_(acB[r]) : sig_(acB[r]);
    float vA1 = __shfl_xor(vA, 1), vA2 = __shfl_xor(vA, 2);
    float vA3 = __shfl_xor(vA2, 1);
    float vB1 = __shfl_xor(vB, 1), vB2 = __shfl_xor(vB, 2);
    float vB3 = __shfl_xor(vB2, 1);
    float iA = gg == 0 ? vA : (gg == 1 ? vA1 : (gg == 2 ? vA2 : vA3));
    float fA = gg == 1 ? vA : (gg == 0 ? vA1 : (gg == 3 ? vA2 : vA3));
    float gA = gg == 2 ? vA : (gg == 3 ? vA1 : (gg == 0 ? vA2 : vA3));
    float oA = gg == 3 ? vA : (gg == 2 ? vA1 : (gg == 1 ? vA2 : vA3));
    float iB = gg == 0 ? vB : (gg == 1 ? vB1 : (gg == 2 ? vB2 : vB3));
    float fB = gg == 1 ? vB : (gg == 0 ? vB1 : (gg == 3 ? vB2 : vB3));
    float gB = gg == 2 ? vB : (gg == 3 ? vB1 : (gg == 0 ? vB2 : vB3));
    float oB = gg == 3 ? vB : (gg == 2 ? vB1 : (gg == 1 ? vB2 : vB3));
    float cA = fA * cstA[r] + iA * gA; cstA[r] = cA;
    float cB = fB * cstB[r] + iB * gB; cstB[r] = cB;
    float hA = oA * tnh_(cA);
    float hB = oB * tnh_(cB);
    u32 pk = (u32)f2bf(hA) | ((u32)f2bf(hB) << 16);
    hpack = (r == gg) ? pk : hpack;   // each lane exports its own-gate batch
  }
  // distribute: posting lane l -> (batch m=l&15, u64-slot db=l>>4, db<3)
  const int m_ = lane & 15, db = lane >> 4;
  u32 w0, w1, w2;
  {
    int jp0 = 3 * db, jp1 = jp0 + 1, jp2 = jp0 + 2;
    int sb = ((m_ >> 2) << 4) + (m_ & 3);
    u32 t0 = (u32)__builtin_amdgcn_ds_bpermute((sb + ((jp0 & 3) << 2)) << 2, (int)hpack);
    u32 t1 = (u32)__builtin_amdgcn_ds_bpermute((sb + ((jp1 & 3) << 2)) << 2, (int)hpack);
    u32 t2 = (u32)__builtin_amdgcn_ds_bpermute((sb + ((jp2 & 3) << 2)) << 2, (int)hpack);
    w0 = (jp0 & 4) ? (t0 >> 16) : (t0 & 0xFFFFu);
    w1 = (jp1 & 4) ? (t1 >> 16) : (t1 & 0xFFFFu);
    w2 = (jp2 & 4) ? (t2 >> 16) : (t2 & 0xFFFFu);
  }
  if (db < 3) {
    u64 val = ((u64)etag) << 48;
    val |= (u64)w0;
    val |= ((u64)w1) << 16;
    if (db != 2) val |= ((u64)w2) << 32;
    u64 elem = blk * BSTRIDE + (u64)(m_ * 12 + wv * 3 + db);
    __hip_atomic_store(exch + elem, val,
                       __ATOMIC_RELAXED, __HIP_MEMORY_SCOPE_AGENT);
  }
}

extern "C" __global__ void __launch_bounds__(256, 1)
lstm_fused(const int* __restrict__ tokens, const void* __restrict__ emb,
           const void* __restrict__ W0, const void* __restrict__ R0, const void* __restrict__ b0,
           const void* __restrict__ W1, const void* __restrict__ R1, const void* __restrict__ b1,
           const void* __restrict__ Wout, const void* __restrict__ bout,
           void* __restrict__ outv) {
  extern __shared__ char smem[];

  const int tid = threadIdx.x;
  const int b = blockIdx.x;
  const int g = b & (NG - 1);
  const int w = b >> 4;
  const int role = w >> 3;             // 0 = layer-0 wg, 1 = layer-1 wg
  const int sl = w & 7;
  const int isF32 = g_isF32;
  const u32 tagB = ((u32)g_run) << 10;

  auto ldf = [&](const void* p, int idx) -> float {
    return isF32 ? ((const float*)p)[idx] : bf2f(((const u16*)p)[idx]);
  };

  const int lane = tid & 63;
  const int wv = tid >> 6;            // wave owns units [8wv, 8wv+8) all gates
  const int ml = lane & 15;
  const int quad = lane >> 4;
  const int um = tid >> 4;
  const int un = tid & 15;

  // unit-major column permutation: local col n -> global z-col
  auto colg = [&](int n) -> int {
    return ((n & 3) << 8) + (sl << 5) + (n >> 2);
  };

  int* flp = g_pr + (g << 3) * 16;
  int dead = 0;

  if (role == 0) {
    // ================= LAYER-0 WORKGROUP =================
    u16* w0t = (u16*)(smem + L0_W0T);
    u16* r0t = (u16*)(smem + L0_R0T);
    u16* ldsX = (u16*)(smem + L0_X);
    u16* stg = (u16*)(smem + L0_STG);
    float* ldsB = (float*)(smem + L0_B);

    for (int i = tid; i < 128 * 128; i += 256) {
      int k = i >> 7, n = i & 127;
      w0t[n * EPAD + k] = f2bf(ldf(W0, k * 1024 + colg(n)));
    }
    for (int i = tid; i < 128 * 256; i += 256) {
      int k = i >> 7, n = i & 127;
      r0t[n * HS + k] = f2bf(ldf(R0, k * 1024 + colg(n)));
    }
    if (tid < 128) ldsB[tid] = ldf(b0, colg(tid));

    float cstA[4] = {0.f, 0.f, 0.f, 0.f};
    float cstB[4] = {0.f, 0.f, 0.f, 0.f};
    const int tokBase = (g * MB + um) * T_STEPS;
    int prMin = 0;                    // cached min L1 progress (ring guard)

    float4 xfA, xfB; uint4 xbf;
    {
      int tok = tokens[tokBase];
      if (isF32) {
        const float* row = (const float*)emb + (u64)tok * E_SZ + (un << 3);
        xfA = *(const float4*)row; xfB = *(const float4*)(row + 4);
      } else {
        xbf = *(const uint4*)((const u16*)emb + (u64)tok * E_SZ + (un << 3));
      }
    }
    __syncthreads();

    const int row0 = (wv << 5) + ml;
    const u16* brA0 = w0t + row0 * EPAD + (quad << 3);
    const u16* brB0 = brA0 + (EPAD << 4);
    const u16* brA2 = r0t + row0 * HS + (quad << 3);
    const u16* brB2 = brA2 + (HS << 4);

    for (int t = 0; t < T_STEPS; t++) {
      // ring guard at top: off the post critical path
      if (t >= RD && prMin < t - RD + 1)
        prMin = wavePollMin(flp, t - RD + 1, lane, dead);

      // commit x_t
      {
        uint4 pk;
        if (isF32) {
          pk.x = (u32)f2bf(xfA.x) | ((u32)f2bf(xfA.y) << 16);
          pk.y = (u32)f2bf(xfA.z) | ((u32)f2bf(xfA.w) << 16);
          pk.z = (u32)f2bf(xfB.x) | ((u32)f2bf(xfB.y) << 16);
          pk.w = (u32)f2bf(xfB.z) | ((u32)f2bf(xfB.w) << 16);
        } else pk = xbf;
        *(uint4*)(ldsX + um * EPAD + (un << 3)) = pk;
      }
      __syncthreads();   // B1: x visible; prev stg reads done before here

      float ba = ldsB[row0], bb = ldsB[row0 + 16];
      f32x4 acA = {ba, ba, ba, ba}, acB = {bb, bb, bb, bb};

      // x_t @ W0 (no dependence on h0)
      {
        const u16* ar = ldsX + ml * EPAD + (quad << 3);
#pragma unroll
        for (int kc = 0; kc < 4; kc++) {
          bf16x8 av = *(const bf16x8*)(ar + kc * 32);
          acA = __builtin_amdgcn_mfma_f32_16x16x32_bf16(av, *(const bf16x8*)(brA0 + kc * 32), acA, 0, 0, 0);
          acB = __builtin_amdgcn_mfma_f32_16x16x32_bf16(av, *(const bf16x8*)(brB0 + kc * 32), acB, 0, 0, 0);
        }
      }

      // h0_{t-1}: wave-split staged gather -> stg
      if (t > 0) {
        const u64* base = g_exH0 +
            (u64)((((t - 1) & (RD - 1)) * NG + g) * NSL) * BSTRIDE;
        stageOne(base, (tagB + t) & 0xFFFFu, stg, wv, ml, quad, dead);
      }
      __syncthreads();   // B2: stg visible to all waves

      if (t > 0) {
#pragma unroll
        for (int j = 0; j < NSL; j++) {
          bf16x8 fv = *(const bf16x8*)(stg + (((j << 4) + ml) * 4 + quad) * 8);
          acA = __builtin_amdgcn_mfma_f32_16x16x32_bf16(fv, *(const bf16x8*)(brA2 + (j << 5)), acA, 0, 0, 0);
          acB = __builtin_amdgcn_mfma_f32_16x16x32_bf16(fv, *(const bf16x8*)(brB2 + (j << 5)), acB, 0, 0, 0);
        }
      }

      // in-wave gates + cell + post (no barrier, no ldsG)
      gateCellPost(acA, acB, cstA, cstB, lane, wv, (tagB + t + 1) & 0xFFFFu,
                   g_exH0, (u64)(((t & (RD - 1)) * NG + g) * NSL + sl));

      // x_{t+1} prefetch in flight across next rendezvous
      if (t + 1 < T_STEPS) {
        int tok = tokens[tokBase + t + 1];
        if (isF32) {
          const float* row = (const float*)emb + (u64)tok * E_SZ + (un << 3);
          xfA = *(const float4*)row; xfB = *(const float4*)(row + 4);
        } else {
          xbf = *(const uint4*)((const u16*)emb + (u64)tok * E_SZ + (un << 3));
        }
      }
    }
  } else {
    // ================= LAYER-1 WORKGROUP =================
    u16* w1t = (u16*)(smem + L1_W1T);
    u16* r1t = (u16*)(smem + L1_R1T);
    u16* stg0 = (u16*)(smem + L1_SG0);
    u16* stg1 = (u16*)(smem + L1_SG1);
    float* ldsB = (float*)(smem + L1_B);

    for (int i = tid; i < 128 * 256; i += 256) {
      int k = i >> 7, n = i & 127;
      w1t[n * HS + k] = f2bf(ldf(W1, k * 1024 + colg(n)));
      r1t[n * HS + k] = f2bf(ldf(R1, k * 1024 + colg(n)));
    }
    if (tid < 128) ldsB[tid] = ldf(b1, colg(tid));
    __syncthreads();

    float cstA[4] = {0.f, 0.f, 0.f, 0.f};
    float cstB[4] = {0.f, 0.f, 0.f, 0.f};
    const int row0 = (wv << 5) + ml;
    const u16* brA1 = w1t + row0 * HS + (quad << 3);
    const u16* brB1 = brA1 + (HS << 4);
    const u16* brA2 = r1t + row0 * HS + (quad << 3);
    const u16* brB2 = brA2 + (HS << 4);

    for (int t = 0; t < T_STEPS; t++) {
      // fused wave-split staged gather: h0_t + h1_{t-1}
      {
        const u64* h0base = g_exH0 +
            (u64)(((t & (RD - 1)) * NG + g) * NSL) * BSTRIDE;
        const u64* h1base = g_exH1 +
            (u64)((((t - 1) & 1) * NG + g) * NSL) * BSTRIDE;
        stageDual(h0base, (tagB + t + 1) & 0xFFFFu, stg0,
                  h1base, (tagB + t) & 0xFFFFu, stg1, (t > 0),
                  wv, ml, quad, dead);
      }
      __syncthreads();   // B1: staging visible

      // ring-slot release immediately after staging barrier
      if (tid == 0) {
        __atomic_signal_fence(__ATOMIC_RELEASE);
        __hip_atomic_store(g_pr + ((g << 3) + sl) * 16, t + 1,
                           __ATOMIC_RELAXED, __HIP_MEMORY_SCOPE_AGENT);
      }

      float ba = ldsB[row0], bb = ldsB[row0 + 16];
      f32x4 acA = {ba, ba, ba, ba}, acB = {bb, bb, bb, bb};

      // h0_t @ W1
#pragma unroll
      for (int j = 0; j < NSL; j++) {
        bf16x8 fv = *(const bf16x8*)(stg0 + (((j << 4) + ml) * 4 + quad) * 8);
        acA = __builtin_amdgcn_mfma_f32_16x16x32_bf16(fv, *(const bf16x8*)(brA1 + (j << 5)), acA, 0, 0, 0);
        acB = __builtin_amdgcn_mfma_f32_16x16x32_bf16(fv, *(const bf16x8*)(brB1 + (j << 5)), acB, 0, 0, 0);
      }
      // h1_{t-1} @ R1
      if (t > 0) {
#pragma unroll
        for (int j = 0; j < NSL; j++) {
          bf16x8 fv = *(const bf16x8*)(stg1 + (((j << 4) + ml) * 4 + quad) * 8);
          acA = __builtin_amdgcn_mfma_f32_16x16x32_bf16(fv, *(const bf16x8*)(brA2 + (j << 5)), acA, 0, 0, 0);
          acB = __builtin_amdgcn_mfma_f32_16x16x32_bf16(fv, *(const bf16x8*)(brB2 + (j << 5)), acB, 0, 0, 0);
        }
      }

      // in-wave gates + cell + post
      gateCellPost(acA, acB, cstA, cstB, lane, wv, (tagB + t + 1) & 0xFFFFu,
                   g_exH1, (u64)(((t & 1) * NG + g) * NSL + sl));

      __syncthreads();   // B2: stg reads done before next stageDual writes
    }

    // epilogue: logits from h1_{T-1}
    if (sl == 0) {
      u16* ldsEpi = stg0;   // 8448B needed <= 16384B of SG0+SG1
      float* woutf = (float*)(smem + L1_EPIF);
      float* red = woutf + 272;
      const u32 etag = (tagB + T_STEPS) & 0xFFFFu;
      const int mB = tid >> 4;
      const int uS = tid & 15;
      const int qS = uS / 3;
      const int sS = uS - qS * 3;
      const int kb = (qS << 3) + 3 * sS;
      const int nFull = (sS != 2);
      if (uS < 12) {
        for (int sp = 0; sp < 8; sp++) {
          const u64* p = g_exH1 +
              (u64)(((1) * NG + g) * NSL + sp) * BSTRIDE + mB * 12 + uS;
          u64 v; int it = 0;
          while (true) {
            v = ldAtom(p);
            if ((u32)(v >> 48) == etag) break;
            if (dead) break;
            if (++it > POLL_BAIL) { dead = 1; break; }
            if (it > 8) __builtin_amdgcn_s_sleep(1);
          }
          u16* dst = ldsEpi + mB * HS + (sp << 5) + kb;
          dst[0] = (u16)v;
          dst[1] = (u16)(v >> 16);
          if (nFull) dst[2] = (u16)(v >> 32);
        }
      }
      __syncthreads();
      woutf[tid] = ldf(Wout, tid);
      __syncthreads();
      float p = 0.f;
#pragma unroll
      for (int j = 0; j < 16; j++)
        p += bf2f(ldsEpi[um * HS + (un << 4) + j]) * woutf[(un << 4) + j];
      red[um * 17 + un] = p;
      __syncthreads();
      if (tid < 16) {
        float sum = ldf(bout, 0);
#pragma unroll
        for (int j = 0; j < 16; j++) sum += red[tid * 17 + j];
        float val = sig_(sum);
        if (isF32) ((float*)outv)[g * MB + tid] = val;
        else       ((u16*)outv)[g * MB + tid] = f2bf(val);
      }
    }
  }
}

extern "C" void kernel_launch(void* const* d_in, const int* in_sizes, int n_in,
                              void* d_out, int out_size, void* d_ws, size_t ws_size,
                              hipStream_t stream) {
  const int* tokens = (const int*)d_in[0];
  const void* emb  = d_in[1];
  const void* W0   = d_in[2];
  const void* R0   = d_in[3];
  const void* b0   = d_in[4];
  const void* W1   = d_in[5];
  const void* R1   = d_in[6];
  const void* b1   = d_in[7];
  const void* Wout = d_in[8];
  const void* bout = d_in[9];

  hipFuncSetAttribute((const void*)lstm_fused,
                      hipFuncAttributeMaxDynamicSharedMemorySize, SMEM_TOTAL);

  dtype_probe<<<dim3(1), dim3(256), 0, stream>>>(W0);

  // 256 wgs (16 groups x (8 L0 + 8 L1)), 1 wg/CU: co-resident.
  lstm_fused<<<dim3(256), dim3(256), SMEM_TOTAL, stream>>>(
      tokens, emb, W0, R0, b0, W1, R1, b1, Wout, bout, d_out);
}

// Round 9
// 3182.119 us; speedup vs baseline: 1.2277x; 1.2277x over previous
//
#include <hip/hip_runtime.h>

typedef unsigned short u16;
typedef unsigned int u32;
typedef unsigned long long u64;
typedef __attribute__((ext_vector_type(8))) short bf16x8;   // 8 bf16 (4 VGPRs)
typedef __attribute__((ext_vector_type(4))) float f32x4;

#define T_STEPS 1024
#define E_SZ 128
#define U_SZ 256

#define NG 16    // batch groups (16 batches each)
#define MB 16    // batch rows per group
#define NSL 8    // slices per layer (8 L0-wgs + 8 L1-wgs per group)
#define RD 8     // h0 ring depth
#define HS 264   // epilogue LDS row stride (u16)
#define EPAD 136 // padded LDS row stride for x, K=128
#define BSTRIDE 192  // u64 per slice-block: 16 batches x 12 tagged u64

#define POLL_BAIL 60000   // latched fast-fail: broken protocol -> quick wrong answer

// ---- LDS layout (role-dependent), bytes ----
// Weights/stg in MFMA-FRAGMENT ORDER: lane l reads base + l*16 (bank-
// conflict-free; old row-major + pad had 8-way conflicts on every b128).
#define L0_W0T 0
#define L0_R0T 32768
#define L0_X   98304
#define L0_STG 102656
#define L0_G   110848
#define L0_B   119616
#define L1_W1T 0
#define L1_R1T 65536
#define L1_SG0 131072
#define L1_SG1 139264
#define L1_G   147456
#define L1_B   156224
#define SMEM_TOTAL 156800

// ---- exchange state: self-verifying tagged u64 = {3x bf16 | tag16} ----
// Wire format + protocol UNCHANGED since R2 (proven). R7 wave-split staged
// gather (4x MALL traffic cut). R8 lesson: scattered per-wave posts double
// WRITE_SIZE; keep coalesced 192-thread post.
__device__ u64 g_exH0[RD * NG * NSL * BSTRIDE];  // 1.5 MiB h0 ring
__device__ u64 g_exH1[2 * NG * NSL * BSTRIDE];   // h1 parity ring
__device__ int g_pr[NG * NSL * 16];              // L1 consume progress (ring guard)
__device__ u32 g_run;                            // run/generation counter
__device__ int g_isF32;

__device__ __forceinline__ float bf2f(u16 u) {
  union { u32 i; float f; } v; v.i = ((u32)u) << 16; return v.f;
}
__device__ __forceinline__ u16 f2bf(float f) {
  union { u32 i; float f; } v; v.f = f;
  u32 r = v.i + 0x7fffu + ((v.i >> 16) & 1u);
  return (u16)(r >> 16);
}
__device__ __forceinline__ float sig_(float x) { return 1.f / (1.f + __expf(-x)); }
__device__ __forceinline__ float tnh_(float x) { return 2.f / (1.f + __expf(-2.f * x)) - 1.f; }

// ---- dtype probe: bumps run counter, zeroes ring guard ----
extern "C" __global__ void dtype_probe(const void* W0v) {
  __shared__ int cntBig;
  if (threadIdx.x == 0) cntBig = 0;
  __syncthreads();
  const u16* u = (const u16*)W0v;
  int big = 0;
  for (int i = threadIdx.x; i < 4096; i += 256)
    if ((u[i] & 0x7F80u) >= 0x4100u) big++;
  atomicAdd(&cntBig, big);
  __syncthreads();
  for (int i = threadIdx.x; i < NG * NSL * 16; i += 256) g_pr[i] = 0;
  if (threadIdx.x == 0) {
    g_isF32 = (cntBig > 100) ? 1 : 0;
    g_run = g_run + 1;               // fresh tag generation each launch
  }
}

__device__ __forceinline__ u64 ldAtom(const u64* p) {
  return __hip_atomic_load(p, __ATOMIC_RELAXED, __HIP_MEMORY_SCOPE_AGENT);
}

// ---- ring-guard poll returning min observed progress (amortizes re-polls) ----
__device__ __forceinline__ int wavePollMin(const int* fA, int tgt, int lane,
                                           int& dead) {
  if (dead) return tgt;
  const int* p = (lane < 8) ? fA + lane * 16 : nullptr;
  int ok = (p == nullptr);
  int v = 0x7fffffff;
  int it = 0;
  while (!__all(ok)) {
    if (!ok) {
      v = __hip_atomic_load(p, __ATOMIC_RELAXED, __HIP_MEMORY_SCOPE_AGENT);
      ok = v >= tgt;
    }
    if (++it > POLL_BAIL) { dead = 1; break; }
    if (it > 48) __builtin_amdgcn_s_sleep(1);
  }
  __atomic_signal_fence(__ATOMIC_ACQUIRE);
  int m = (lane < 8) ? v : 0x7fffffff;
#pragma unroll
  for (int off = 4; off; off >>= 1) {
    int o = __shfl_down(m, off);
    m = m < o ? m : o;
  }
  return __shfl(m, 0);
}

// ---- unpack 3 tagged u64 -> 16B fragment, write to LDS staging.
// Fragment order: slot = slice*64 + quad*16 + ml (writer lanes contiguous,
// reader lane l reads slot l of its slice: conflict-free both sides). ----
__device__ __forceinline__ void unpackToLds(const u64 q0, const u64 q1, const u64 q2,
                                            u16* __restrict__ stg, int slice,
                                            int ml, int quad) {
  u32 a0 = (u32)q0, a1 = (u32)(q0 >> 32);
  u32 b0 = (u32)q1, b1 = (u32)(q1 >> 32);
  u32 c0 = (u32)q2;
  uint4 F;
  F.x = a0;
  F.y = (a1 & 0xFFFFu) | (b0 << 16);
  F.z = (b0 >> 16) | (b1 << 16);
  F.w = c0;
  *(uint4*)(stg + (((slice << 6) + (quad << 4) + ml) << 3)) = F;
}

// ---- wave-split staged gather, ONE ring: wave wv polls+stages slices
// {2wv, 2wv+1}; lane (ml,quad) owns 3 u64 per slice. ----
__device__ __forceinline__ void stageOne(const u64* __restrict__ base, u32 etag,
                                         u16* __restrict__ stg,
                                         int wv, int ml, int quad, int& dead) {
  const int j0 = wv << 1;
  const u64* p0 = base + (u64)j0 * BSTRIDE + ml * 12 + quad * 3;
  const u64* p1 = p0 + BSTRIDE;
  u64 qa0 = ldAtom(p0), qa1 = ldAtom(p0 + 1), qa2 = ldAtom(p0 + 2);
  u64 qb0 = ldAtom(p1), qb1 = ldAtom(p1 + 1), qb2 = ldAtom(p1 + 2);
  int it = 0;
  while (true) {
    u32 badA = (((u32)(qa0 >> 48)) ^ etag) | (((u32)(qa1 >> 48)) ^ etag) |
               (((u32)(qa2 >> 48)) ^ etag);
    u32 badB = (((u32)(qb0 >> 48)) ^ etag) | (((u32)(qb1 >> 48)) ^ etag) |
               (((u32)(qb2 >> 48)) ^ etag);
    if (!__any((badA | badB) != 0)) break;
    if (dead) break;
    if (++it > POLL_BAIL) { dead = 1; break; }
    if (badA) { qa0 = ldAtom(p0); qa1 = ldAtom(p0 + 1); qa2 = ldAtom(p0 + 2); }
    if (badB) { qb0 = ldAtom(p1); qb1 = ldAtom(p1 + 1); qb2 = ldAtom(p1 + 2); }
    if (it > 8) __builtin_amdgcn_s_sleep(1);
  }
  __atomic_signal_fence(__ATOMIC_ACQUIRE);
  unpackToLds(qa0, qa1, qa2, stg, j0, ml, quad);
  unpackToLds(qb0, qb1, qb2, stg, j0 + 1, ml, quad);
}

// ---- wave-split staged gather, BOTH rings fused (L1) ----
__device__ __forceinline__ void stageDual(const u64* __restrict__ b0, u32 e0,
                                          u16* __restrict__ s0,
                                          const u64* __restrict__ b1, u32 e1,
                                          u16* __restrict__ s1, int doH1,
                                          int wv, int ml, int quad, int& dead) {
  const int j0 = wv << 1;
  const int off = ml * 12 + quad * 3;
  const u64* p0a = b0 + (u64)j0 * BSTRIDE + off;
  const u64* p0b = p0a + BSTRIDE;
  const u64* p1a = b1 + (u64)j0 * BSTRIDE + off;
  const u64* p1b = p1a + BSTRIDE;
  u64 xa0 = ldAtom(p0a), xa1 = ldAtom(p0a + 1), xa2 = ldAtom(p0a + 2);
  u64 xb0 = ldAtom(p0b), xb1 = ldAtom(p0b + 1), xb2 = ldAtom(p0b + 2);
  u64 ya0 = 0, ya1 = 0, ya2 = 0, yb0 = 0, yb1 = 0, yb2 = 0;
  if (doH1) {
    ya0 = ldAtom(p1a); ya1 = ldAtom(p1a + 1); ya2 = ldAtom(p1a + 2);
    yb0 = ldAtom(p1b); yb1 = ldAtom(p1b + 1); yb2 = ldAtom(p1b + 2);
  }
  int it = 0;
  while (true) {
    u32 badA = (((u32)(xa0 >> 48)) ^ e0) | (((u32)(xa1 >> 48)) ^ e0) |
               (((u32)(xa2 >> 48)) ^ e0);
    u32 badB = (((u32)(xb0 >> 48)) ^ e0) | (((u32)(xb1 >> 48)) ^ e0) |
               (((u32)(xb2 >> 48)) ^ e0);
    u32 badC = 0, badD = 0;
    if (doH1) {
      badC = (((u32)(ya0 >> 48)) ^ e1) | (((u32)(ya1 >> 48)) ^ e1) |
             (((u32)(ya2 >> 48)) ^ e1);
      badD = (((u32)(yb0 >> 48)) ^ e1) | (((u32)(yb1 >> 48)) ^ e1) |
             (((u32)(yb2 >> 48)) ^ e1);
    }
    if (!__any((badA | badB | badC | badD) != 0)) break;
    if (dead) break;
    if (++it > POLL_BAIL) { dead = 1; break; }
    if (badA) { xa0 = ldAtom(p0a); xa1 = ldAtom(p0a + 1); xa2 = ldAtom(p0a + 2); }
    if (badB) { xb0 = ldAtom(p0b); xb1 = ldAtom(p0b + 1); xb2 = ldAtom(p0b + 2); }
    if (badC) { ya0 = ldAtom(p1a); ya1 = ldAtom(p1a + 1); ya2 = ldAtom(p1a + 2); }
    if (badD) { yb0 = ldAtom(p1b); yb1 = ldAtom(p1b + 1); yb2 = ldAtom(p1b + 2); }
    if (it > 8) __builtin_amdgcn_s_sleep(1);
  }
  __atomic_signal_fence(__ATOMIC_ACQUIRE);
  unpackToLds(xa0, xa1, xa2, s0, j0, ml, quad);
  unpackToLds(xb0, xb1, xb2, s0, j0 + 1, ml, quad);
  if (doH1) {
    unpackToLds(ya0, ya1, ya2, s1, j0, ml, quad);
    unpackToLds(yb0, yb1, yb2, s1, j0 + 1, ml, quad);
  }
}

extern "C" __global__ void __launch_bounds__(256, 1)
lstm_fused(const int* __restrict__ tokens, const void* __restrict__ emb,
           const void* __restrict__ W0, const void* __restrict__ R0, const void* __restrict__ b0,
           const void* __restrict__ W1, const void* __restrict__ R1, const void* __restrict__ b1,
           const void* __restrict__ Wout, const void* __restrict__ bout,
           void* __restrict__ outv) {
  extern __shared__ char smem[];

  const int tid = threadIdx.x;
  const int b = blockIdx.x;
  const int g = b & (NG - 1);
  const int w = b >> 4;
  const int role = w >> 3;             // 0 = layer-0 wg, 1 = layer-1 wg
  const int sl = w & 7;
  const int isF32 = g_isF32;
  const u32 tagB = ((u32)g_run) << 10;

  auto ldf = [&](const void* p, int idx) -> float {
    return isF32 ? ((const float*)p)[idx] : bf2f(((const u16*)p)[idx]);
  };

  const int lane = tid & 63;
  const int wv = tid >> 6;            // wave = gate q (output tiles 2wv, 2wv+1)
  const int ml = lane & 15;
  const int quad = lane >> 4;
  const int um = tid >> 4;
  const int un = tid & 15;
  const int lfr = (quad << 4) + ml;   // fragment lane slot (== lane)

  // cell/post thread mapping: (batch mB, slot uS) ; slot uS<12 holds 3 (or 2)
  // consecutive units: q=uS/3, s=uS%3, kb=8q+3s (s<2: 3 units; s==2: 2 units)
  const int mB = tid >> 4;
  const int uS = tid & 15;
  const int qS = uS / 3;
  const int sS = uS - qS * 3;
  const int kb = (qS << 3) + 3 * sS;
  const int nFull = (sS != 2);

  int* flp = g_pr + (g << 3) * 16;
  int dead = 0;

  if (role == 0) {
    // ================= LAYER-0 WORKGROUP =================
    u16* w0t = (u16*)(smem + L0_W0T);
    u16* r0t = (u16*)(smem + L0_R0T);
    u16* ldsX = (u16*)(smem + L0_X);
    u16* stg = (u16*)(smem + L0_STG);
    float* ldsG = (float*)(smem + L0_G);
    float* ldsB = (float*)(smem + L0_B);

    // weights -> fragment-order LDS (conflict-free b128 reads)
    for (int i = tid; i < 128 * 128; i += 256) {
      int k = i >> 7, n = i & 127;
      int col = ((n >> 5) << 8) + (sl << 5) + (n & 31);
      int wv_ = n >> 5, s_ = (n >> 4) & 1, ml_ = n & 15;
      int j_ = k >> 5, q_ = (k >> 3) & 3, e_ = k & 7;
      int dst = ((((wv_ << 1) + s_) * 4 + j_) * 64 + (q_ << 4) + ml_) * 8 + e_;
      w0t[dst] = f2bf(ldf(W0, k * 1024 + col));
    }
    for (int i = tid; i < 128 * 256; i += 256) {
      int k = i >> 7, n = i & 127;
      int col = ((n >> 5) << 8) + (sl << 5) + (n & 31);
      int wv_ = n >> 5, s_ = (n >> 4) & 1, ml_ = n & 15;
      int j_ = k >> 5, q_ = (k >> 3) & 3, e_ = k & 7;
      int dst = ((((wv_ << 1) + s_) * 8 + j_) * 64 + (q_ << 4) + ml_) * 8 + e_;
      r0t[dst] = f2bf(ldf(R0, k * 1024 + col));
    }
    if (tid < 128) {
      int col = ((tid >> 5) << 8) + (sl << 5) + (tid & 31);
      ldsB[tid] = ldf(b0, col);
    }

    float cst[3] = {0.f, 0.f, 0.f};
    const int tokBase = (g * MB + um) * T_STEPS;
    int prMin = 0;                    // cached min L1 progress (ring guard)

    float4 xfA, xfB; uint4 xbf;
    {
      int tok = tokens[tokBase];
      if (isF32) {
        const float* row = (const float*)emb + (u64)tok * E_SZ + (un << 3);
        xfA = *(const float4*)row; xfB = *(const float4*)(row + 4);
      } else {
        xbf = *(const uint4*)((const u16*)emb + (u64)tok * E_SZ + (un << 3));
      }
    }
    __syncthreads();

    const int row0 = (wv << 5) + ml;
    const u16* brA0 = w0t + (u32)(((wv << 1) + 0) * 256 + lfr) * 8;  // +kc*512
    const u16* brB0 = w0t + (u32)(((wv << 1) + 1) * 256 + lfr) * 8;
    const u16* brA2 = r0t + (u32)(((wv << 1) + 0) * 512 + lfr) * 8;  // +j*512
    const u16* brB2 = r0t + (u32)(((wv << 1) + 1) * 512 + lfr) * 8;

    for (int t = 0; t < T_STEPS; t++) {
      // ring guard at top: off the post critical path
      if (t >= RD && prMin < t - RD + 1)
        prMin = wavePollMin(flp, t - RD + 1, lane, dead);

      // commit x_t
      {
        uint4 pk;
        if (isF32) {
          pk.x = (u32)f2bf(xfA.x) | ((u32)f2bf(xfA.y) << 16);
          pk.y = (u32)f2bf(xfA.z) | ((u32)f2bf(xfA.w) << 16);
          pk.z = (u32)f2bf(xfB.x) | ((u32)f2bf(xfB.y) << 16);
          pk.w = (u32)f2bf(xfB.z) | ((u32)f2bf(xfB.w) << 16);
        } else pk = xbf;
        *(uint4*)(ldsX + um * EPAD + (un << 3)) = pk;
      }
      __syncthreads();   // B1: x visible

      float ba = ldsB[row0], bb = ldsB[row0 + 16];
      f32x4 acA = {ba, ba, ba, ba}, acB = {bb, bb, bb, bb};

      // x_t @ W0 (no dependence on h0)
      {
        const u16* ar = ldsX + ml * EPAD + (quad << 3);
#pragma unroll
        for (int kc = 0; kc < 4; kc++) {
          bf16x8 av = *(const bf16x8*)(ar + kc * 32);
          acA = __builtin_amdgcn_mfma_f32_16x16x32_bf16(av, *(const bf16x8*)(brA0 + (kc << 9)), acA, 0, 0, 0);
          acB = __builtin_amdgcn_mfma_f32_16x16x32_bf16(av, *(const bf16x8*)(brB0 + (kc << 9)), acB, 0, 0, 0);
        }
      }

      // h0_{t-1}: wave-split staged gather -> stg (fragment order)
      if (t > 0) {
        const u64* base = g_exH0 +
            (u64)((((t - 1) & (RD - 1)) * NG + g) * NSL) * BSTRIDE;
        stageOne(base, (tagB + t) & 0xFFFFu, stg, wv, ml, quad, dead);
      }
      __syncthreads();   // B2: stg visible to all waves

      if (t > 0) {
#pragma unroll
        for (int j = 0; j < NSL; j++) {
          bf16x8 fv = *(const bf16x8*)(stg + (((j << 6) + lfr) << 3));
          acA = __builtin_amdgcn_mfma_f32_16x16x32_bf16(fv, *(const bf16x8*)(brA2 + (j << 9)), acA, 0, 0, 0);
          acB = __builtin_amdgcn_mfma_f32_16x16x32_bf16(fv, *(const bf16x8*)(brB2 + (j << 9)), acB, 0, 0, 0);
        }
      }

      // gates
#pragma unroll
      for (int r = 0; r < 4; r++) {
        int m = (quad << 2) + r;
        float gA = (wv == 2) ? tnh_(acA[r]) : sig_(acA[r]);
        float gB = (wv == 2) ? tnh_(acB[r]) : sig_(acB[r]);
        ldsG[row0 * 17 + m] = gA;
        ldsG[(row0 + 16) * 17 + m] = gB;
      }
      __syncthreads();

      // cell update -> direct tagged post (fire-and-forget, coalesced)
      if (uS < 12) {
        u64 val = ((u64)((tagB + t + 1) & 0xFFFFu)) << 48;
#pragma unroll
        for (int i2 = 0; i2 < 3; i2++) {
          if (i2 < 2 || nFull) {
            int k = kb + i2;
            float iv = ldsG[k * 17 + mB];
            float fv = ldsG[(32 + k) * 17 + mB];
            float gv = ldsG[(64 + k) * 17 + mB];
            float ov = ldsG[(96 + k) * 17 + mB];
            float c = fv * cst[i2] + iv * gv; cst[i2] = c;
            val |= ((u64)f2bf(ov * tnh_(c))) << (16 * i2);
          }
        }
        u64 elem = (u64)(((t & (RD - 1)) * NG + g) * NSL + sl) * BSTRIDE +
                   mB * 12 + uS;
        __hip_atomic_store(g_exH0 + elem, val,
                           __ATOMIC_RELAXED, __HIP_MEMORY_SCOPE_AGENT);
      }

      // x_{t+1} prefetch in flight across next rendezvous
      if (t + 1 < T_STEPS) {
        int tok = tokens[tokBase + t + 1];
        if (isF32) {
          const float* row = (const float*)emb + (u64)tok * E_SZ + (un << 3);
          xfA = *(const float4*)row; xfB = *(const float4*)(row + 4);
        } else {
          xbf = *(const uint4*)((const u16*)emb + (u64)tok * E_SZ + (un << 3));
        }
      }
    }
  } else {
    // ================= LAYER-1 WORKGROUP =================
    u16* w1t = (u16*)(smem + L1_W1T);
    u16* r1t = (u16*)(smem + L1_R1T);
    u16* stg0 = (u16*)(smem + L1_SG0);
    u16* stg1 = (u16*)(smem + L1_SG1);
    float* ldsG = (float*)(smem + L1_G);
    float* ldsB = (float*)(smem + L1_B);

    for (int i = tid; i < 128 * 256; i += 256) {
      int k = i >> 7, n = i & 127;
      int col = ((n >> 5) << 8) + (sl << 5) + (n & 31);
      int wv_ = n >> 5, s_ = (n >> 4) & 1, ml_ = n & 15;
      int j_ = k >> 5, q_ = (k >> 3) & 3, e_ = k & 7;
      int dst = ((((wv_ << 1) + s_) * 8 + j_) * 64 + (q_ << 4) + ml_) * 8 + e_;
      w1t[dst] = f2bf(ldf(W1, k * 1024 + col));
      r1t[dst] = f2bf(ldf(R1, k * 1024 + col));
    }
    if (tid < 128) {
      int col = ((tid >> 5) << 8) + (sl << 5) + (tid & 31);
      ldsB[tid] = ldf(b1, col);
    }
    __syncthreads();

    float cst[3] = {0.f, 0.f, 0.f};
    const int row0 = (wv << 5) + ml;
    const u16* brA1 = w1t + (u32)(((wv << 1) + 0) * 512 + lfr) * 8;
    const u16* brB1 = w1t + (u32)(((wv << 1) + 1) * 512 + lfr) * 8;
    const u16* brA2 = r1t + (u32)(((wv << 1) + 0) * 512 + lfr) * 8;
    const u16* brB2 = r1t + (u32)(((wv << 1) + 1) * 512 + lfr) * 8;

    for (int t = 0; t < T_STEPS; t++) {
      // fused wave-split staged gather: h0_t + h1_{t-1}
      {
        const u64* h0base = g_exH0 +
            (u64)(((t & (RD - 1)) * NG + g) * NSL) * BSTRIDE;
        const u64* h1base = g_exH1 +
            (u64)((((t - 1) & 1) * NG + g) * NSL) * BSTRIDE;
        stageDual(h0base, (tagB + t + 1) & 0xFFFFu, stg0,
                  h1base, (tagB + t) & 0xFFFFu, stg1, (t > 0),
                  wv, ml, quad, dead);
      }
      __syncthreads();   // B1: staging visible

      // ring-slot release immediately after staging barrier
      if (tid == 0) {
        __atomic_signal_fence(__ATOMIC_RELEASE);
        __hip_atomic_store(g_pr + ((g << 3) + sl) * 16, t + 1,
                           __ATOMIC_RELAXED, __HIP_MEMORY_SCOPE_AGENT);
      }

      float ba = ldsB[row0], bb = ldsB[row0 + 16];
      f32x4 acA = {ba, ba, ba, ba}, acB = {bb, bb, bb, bb};

      // h0_t @ W1
#pragma unroll
      for (int j = 0; j < NSL; j++) {
        bf16x8 fv = *(const bf16x8*)(stg0 + (((j << 6) + lfr) << 3));
        acA = __builtin_amdgcn_mfma_f32_16x16x32_bf16(fv, *(const bf16x8*)(brA1 + (j << 9)), acA, 0, 0, 0);
        acB = __builtin_amdgcn_mfma_f32_16x16x32_bf16(fv, *(const bf16x8*)(brB1 + (j << 9)), acB, 0, 0, 0);
      }
      // h1_{t-1} @ R1
      if (t > 0) {
#pragma unroll
        for (int j = 0; j < NSL; j++) {
          bf16x8 fv = *(const bf16x8*)(stg1 + (((j << 6) + lfr) << 3));
          acA = __builtin_amdgcn_mfma_f32_16x16x32_bf16(fv, *(const bf16x8*)(brA2 + (j << 9)), acA, 0, 0, 0);
          acB = __builtin_amdgcn_mfma_f32_16x16x32_bf16(fv, *(const bf16x8*)(brB2 + (j << 9)), acB, 0, 0, 0);
        }
      }

      // gates
#pragma unroll
      for (int r = 0; r < 4; r++) {
        int m = (quad << 2) + r;
        float gA = (wv == 2) ? tnh_(acA[r]) : sig_(acA[r]);
        float gB = (wv == 2) ? tnh_(acB[r]) : sig_(acB[r]);
        ldsG[row0 * 17 + m] = gA;
        ldsG[(row0 + 16) * 17 + m] = gB;
      }
      __syncthreads();

      // cell update -> direct tagged post
      if (uS < 12) {
        u64 val = ((u64)((tagB + t + 1) & 0xFFFFu)) << 48;
#pragma unroll
        for (int i2 = 0; i2 < 3; i2++) {
          if (i2 < 2 || nFull) {
            int k = kb + i2;
            float iv = ldsG[k * 17 + mB];
            float fv = ldsG[(32 + k) * 17 + mB];
            float gv = ldsG[(64 + k) * 17 + mB];
            float ov = ldsG[(96 + k) * 17 + mB];
            float c = fv * cst[i2] + iv * gv; cst[i2] = c;
            val |= ((u64)f2bf(ov * tnh_(c))) << (16 * i2);
          }
        }
        u64 elem = (u64)(((t & 1) * NG + g) * NSL + sl) * BSTRIDE +
                   mB * 12 + uS;
        __hip_atomic_store(g_exH1 + elem, val,
                           __ATOMIC_RELAXED, __HIP_MEMORY_SCOPE_AGENT);
      }
      __syncthreads();   // B2: stg/ldsG reads done before next writes
    }

    // epilogue: logits from h1_{T-1} (staging buffers reused as gather area)
    if (sl == 0) {
      u16* ldsEpi = stg0;   // 8448B needed <= 16384B of SG0+SG1
      const u32 etag = (tagB + T_STEPS) & 0xFFFFu;
      if (uS < 12) {
        for (int sp = 0; sp < 8; sp++) {
          const u64* p = g_exH1 +
              (u64)(((1) * NG + g) * NSL + sp) * BSTRIDE + mB * 12 + uS;
          u64 v; int it = 0;
          while (true) {
            v = ldAtom(p);
            if ((u32)(v >> 48) == etag) break;
            if (dead) break;
            if (++it > POLL_BAIL) { dead = 1; break; }
            if (it > 8) __builtin_amdgcn_s_sleep(1);
          }
          u16* dst = ldsEpi + mB * HS + (sp << 5) + kb;
          dst[0] = (u16)v;
          dst[1] = (u16)(v >> 16);
          if (nFull) dst[2] = (u16)(v >> 32);
        }
      }
      __syncthreads();
      float* woutf = ldsG;
      float* red = ldsG + 272;
      woutf[tid] = ldf(Wout, tid);
      __syncthreads();
      float p = 0.f;
#pragma unroll
      for (int j = 0; j < 16; j++)
        p += bf2f(ldsEpi[um * HS + (un << 4) + j]) * woutf[(un << 4) + j];
      red[um * 17 + un] = p;
      __syncthreads();
      if (tid < 16) {
        float sum = ldf(bout, 0);
#pragma unroll
        for (int j = 0; j < 16; j++) sum += red[tid * 17 + j];
        float val = sig_(sum);
        if (isF32) ((float*)outv)[g * MB + tid] = val;
        else       ((u16*)outv)[g * MB + tid] = f2bf(val);
      }
    }
  }
}

extern "C" void kernel_launch(void* const* d_in, const int* in_sizes, int n_in,
                              void* d_out, int out_size, void* d_ws, size_t ws_size,
                              hipStream_t stream) {
  const int* tokens = (const int*)d_in[0];
  const void* emb  = d_in[1];
  const void* W0   = d_in[2];
  const void* R0   = d_in[3];
  const void* b0   = d_in[4];
  const void* W1   = d_in[5];
  const void* R1   = d_in[6];
  const void* b1   = d_in[7];
  const void* Wout = d_in[8];
  const void* bout = d_in[9];

  hipFuncSetAttribute((const void*)lstm_fused,
                      hipFuncAttributeMaxDynamicSharedMemorySize, SMEM_TOTAL);

  dtype_probe<<<dim3(1), dim3(256), 0, stream>>>(W0);

  // 256 wgs (16 groups x (8 L0 + 8 L1)), 1 wg/CU: co-resident.
  lstm_fused<<<dim3(256), dim3(256), SMEM_TOTAL, stream>>>(
      tokens, emb, W0, R0, b0, W1, R1, b1, Wout, bout, d_out);
}